// Round 10
// baseline (17.406 us; speedup 1.0000x reference)
//
#include <hip/hip_runtime.h>
#include <math.h>

#define DIM 1024
#define D4  (DIM / 4)      // 256 float4 per row
#define SNUM 5
#define EPSL 1e-6f
#define MARGINL 1.0f

// (x + eps) - y per element, fma-accumulated (eps pre-folded into anchor regs).
__device__ __forceinline__ float sqe4(const float4& xe, const float4& y) {
    const float dx = xe.x - y.x;
    const float dy = xe.y - y.y;
    const float dz = xe.z - y.z;
    const float dw = xe.w - y.w;
    float s = dx * dx;
    s = fmaf(dy, dy, s);
    s = fmaf(dz, dz, s);
    s = fmaf(dw, dw, s);
    return s;
}

__device__ __forceinline__ float4 adde(const float4& x) {
    return make_float4(x.x + EPSL, x.y + EPSL, x.z + EPSL, x.w + EPSL);
}

// Merged-butterfly primitive: one shfl_xor step reduces across bit m AND merges
// two accumulators (lanes with bit m unset end up owning x's sum, set -> y's).
__device__ __forceinline__ float merge_red(float x, float y, int m, int lane) {
    const float send = (lane & m) ? x : y;
    const float recv = __shfl_xor(send, m, 64);
    const float keep = (lane & m) ? y : x;
    return keep + recv;
}

// Reduce 12 accumulators across 64 lanes in 14 shuffles. Returns the full sum of
// acc id = b2 ? 8+2*b4+b5 : 4*b3+2*b4+b5 in each lane; rep lanes are canonical.
__device__ __forceinline__ float butterfly12(const float* acc, int lane) {
    const float r0 = merge_red(acc[0],  acc[1],  32, lane);
    const float r1 = merge_red(acc[2],  acc[3],  32, lane);
    const float r2 = merge_red(acc[4],  acc[5],  32, lane);
    const float r3 = merge_red(acc[6],  acc[7],  32, lane);
    const float r4 = merge_red(acc[8],  acc[9],  32, lane);
    const float r5 = merge_red(acc[10], acc[11], 32, lane);
    const float s0 = merge_red(r0, r1, 16, lane);
    const float s1 = merge_red(r2, r3, 16, lane);
    const float s2 = merge_red(r4, r5, 16, lane);
    const float t0 = merge_red(s0, s1, 8, lane);
    const float t1 = s2 + __shfl_xor(s2, 8, 64);
    float u = merge_red(t0, t1, 4, lane);
    u += __shfl_xor(u, 2, 64);
    u += __shfl_xor(u, 1, 64);
    return u;
}

// One block (256 threads) per anchor PAIR: 14 row-loads instead of 24 (k1's own
// rows are k0's first negatives; rows k0+2..k0+5 feed both anchors). Gross L2
// traffic 192->114 MB — the binding term once shuffles were fixed (R8) and VALU
// ruled out (R9 null). Two merged butterflies (28 shuffles/wave, half the waves
// of R9 -> same DS total). Cross-wave LDS combine before the nonlinear tail.
__global__ __launch_bounds__(256) void hinge_kernel(const float* __restrict__ vfeat,
                                                    const float* __restrict__ afeat,
                                                    float* __restrict__ bsum,
                                                    int B, int nblocks) {
    // XCD-chunked bijective swizzle (R2: -46%): contiguous anchors per XCD.
    int b = blockIdx.x;
    if ((nblocks & 7) == 0) {
        const int chunk = nblocks >> 3;
        b = (b & 7) * chunk + (b >> 3);
    }
    const int k0 = 2 * b;
    const int k1 = k0 + 1;
    const int t = threadIdx.x;
    const int wave = t >> 6;
    const int lane = t & 63;

    const float4* __restrict__ v4 = reinterpret_cast<const float4*>(vfeat);
    const float4* __restrict__ a4 = reinterpret_cast<const float4*>(afeat);

    const float4 vk0 = v4[(size_t)k0 * D4 + t];
    const float4 ak0 = a4[(size_t)k0 * D4 + t];
    const float4 vk1 = v4[(size_t)k1 * D4 + t];
    const float4 ak1 = a4[(size_t)k1 * D4 + t];
    const float4 vk0e = adde(vk0), ak0e = adde(ak0);
    const float4 vk1e = adde(vk1), ak1e = adde(ak1);

    // acc0: anchor k0 ([0]=pos, [1..5]=n1, [6..10]=n2, [11]=pad); acc1: anchor k1
    float acc0[12], acc1[12];
    acc0[11] = 0.0f; acc1[11] = 0.0f;
    acc0[0] = sqe4(vk0e, ak0);
    acc1[0] = sqe4(vk1e, ak1);

    if (k0 >= SNUM) {
        // fast path: k0's negatives are rows k0+1..k0+5 (k0+1 == k1, in regs),
        // k1's negatives are rows k0+2..k0+6; rows k0+2..k0+5 feed BOTH anchors.
        acc0[1] = sqe4(vk0e, ak1);
        acc0[6] = sqe4(ak0e, vk1);
        #pragma unroll
        for (int r = 2; r <= 6; ++r) {
            int row = k0 + r;
            if (row >= B) row -= B;
            const float4 arow = a4[(size_t)row * D4 + t];
            const float4 vrow = v4[(size_t)row * D4 + t];
            if (r <= 5) {                       // anchor k0, m = r-1
                acc0[r]     = sqe4(vk0e, arow);
                acc0[5 + r] = sqe4(ak0e, vrow);
            }
            acc1[1 + (r - 2)] = sqe4(vk1e, arow); // anchor k1, m = r-2
            acc1[6 + (r - 2)] = sqe4(ak1e, vrow);
        }
    } else {
        // generic path (k0 < SNUM: reference's m==k duplicate breaks contiguity)
        // — only 3 blocks; wave-uniform branch.
        #pragma unroll
        for (int m = 0; m < SNUM; ++m) {
            int t0 = k0 + m + 1; if (m == k0) t0 = k0 + 1; if (t0 >= B) t0 -= B;
            int t1 = k1 + m + 1; if (m == k1) t1 = k1 + 1; if (t1 >= B) t1 -= B;
            const float4 a0 = a4[(size_t)t0 * D4 + t];
            const float4 v0 = v4[(size_t)t0 * D4 + t];
            const float4 a1 = a4[(size_t)t1 * D4 + t];
            const float4 v1 = v4[(size_t)t1 * D4 + t];
            acc0[1 + m] = sqe4(vk0e, a0);
            acc0[6 + m] = sqe4(ak0e, v0);
            acc1[1 + m] = sqe4(vk1e, a1);
            acc1[6 + m] = sqe4(ak1e, v1);
        }
    }

    const float u0 = butterfly12(acc0, lane);
    const float u1 = butterfly12(acc1, lane);

    // lane -> acc id, one canonical representative lane per id
    const int b5 = (lane >> 5) & 1, b4 = (lane >> 4) & 1;
    const int b3 = (lane >> 3) & 1, b2 = (lane >> 2) & 1;
    const int id = b2 ? (8 + 2 * b4 + b5) : (4 * b3 + 2 * b4 + b5);
    const bool rep = ((lane & 3) == 0) && (!b2 || !b3);

    __shared__ float sh[4][24];
    if (rep) {
        sh[wave][id]      = u0;
        sh[wave][12 + id] = u1;
    }
    __syncthreads();

    if (t == 0) {
        float tot[22];
        #pragma unroll
        for (int i = 0; i < 11; ++i) {
            tot[i]      = sh[0][i] + sh[1][i] + sh[2][i] + sh[3][i];
            tot[11 + i] = sh[0][12 + i] + sh[1][12 + i] + sh[2][12 + i] + sh[3][12 + i];
        }
        const float dp0 = sqrtf(tot[0]);
        float dn1_0 = sqrtf(tot[1]), dn2_0 = sqrtf(tot[6]);
        const float dp1 = sqrtf(tot[11]);
        float dn1_1 = sqrtf(tot[12]), dn2_1 = sqrtf(tot[17]);
        #pragma unroll
        for (int m = 1; m < SNUM; ++m) {
            dn1_0 = fminf(dn1_0, sqrtf(tot[1 + m]));
            dn2_0 = fminf(dn2_0, sqrtf(tot[6 + m]));
            dn1_1 = fminf(dn1_1, sqrtf(tot[12 + m]));
            dn2_1 = fminf(dn2_1, sqrtf(tot[17 + m]));
        }
        const float h0 = fmaxf(MARGINL + 2.0f * dp0 - dn1_0 - dn2_0, 0.0f);
        const float h1 = fmaxf(MARGINL + 2.0f * dp1 - dn1_1 - dn2_1, 0.0f);
        bsum[blockIdx.x] = h0 + h1;
    }
}

// Deterministic single-block mean: sum n partials / B.
__global__ __launch_bounds__(1024) void mean_kernel(const float* __restrict__ bsum,
                                                    float* __restrict__ out,
                                                    int n, int B) {
    const int t = threadIdx.x;
    float s = 0.0f;
    for (int i = t; i < n; i += 1024) s += bsum[i];

    #pragma unroll
    for (int off = 32; off > 0; off >>= 1)
        s += __shfl_xor(s, off, 64);

    __shared__ float red[16];
    if ((t & 63) == 0) red[t >> 6] = s;
    __syncthreads();
    if (t == 0) {
        float tot = 0.0f;
        #pragma unroll
        for (int w = 0; w < 16; ++w) tot += red[w];
        out[0] = tot / (float)B;
    }
}

extern "C" void kernel_launch(void* const* d_in, const int* in_sizes, int n_in,
                              void* d_out, int out_size, void* d_ws, size_t ws_size,
                              hipStream_t stream) {
    const float* vfeat = (const float*)d_in[0];
    const float* afeat = (const float*)d_in[1];
    const int B = in_sizes[0] / DIM;
    const int nblocks = B / 2;

    float* bsum = (float*)d_ws;   // nblocks floats of scratch
    float* out  = (float*)d_out;

    hinge_kernel<<<nblocks, 256, 0, stream>>>(vfeat, afeat, bsum, B, nblocks);
    mean_kernel<<<1, 1024, 0, stream>>>(bsum, out, nblocks, B);
}

// Round 11
// 17.317 us; speedup vs baseline: 1.0051x; 1.0051x over previous
//
#include <hip/hip_runtime.h>
#include <math.h>

#define DIM 1024
#define D4  (DIM / 4)      // 256 float4 per row
#define SNUM 5
#define EPSL 1e-6f
#define MARGINL 1.0f

__device__ __forceinline__ float sq4(const float4& x, const float4& y) {
    const float dx = x.x - y.x + EPSL;
    const float dy = x.y - y.y + EPSL;
    const float dz = x.z - y.z + EPSL;
    const float dw = x.w - y.w + EPSL;
    float s = dx * dx;
    s = fmaf(dy, dy, s);
    s = fmaf(dz, dz, s);
    s = fmaf(dw, dw, s);
    return s;
}

// Merged-butterfly primitive: one shfl_xor step reduces across bit m AND merges
// two accumulators (lanes with bit m unset end up owning x's sum, set -> y's).
__device__ __forceinline__ float merge_red(float x, float y, int m, int lane) {
    const float send = (lane & m) ? x : y;
    const float recv = __shfl_xor(send, m, 64);
    const float keep = (lane & m) ? y : x;
    return keep + recv;
}

// Reduce 12 accumulators across 64 lanes in 14 shuffles. Lane ends with the full
// sum of acc id = b2 ? 8+2*b4+b5 : 4*b3+2*b4+b5; rep lanes are canonical.
__device__ __forceinline__ float butterfly12(const float* acc, int lane) {
    const float r0 = merge_red(acc[0],  acc[1],  32, lane);
    const float r1 = merge_red(acc[2],  acc[3],  32, lane);
    const float r2 = merge_red(acc[4],  acc[5],  32, lane);
    const float r3 = merge_red(acc[6],  acc[7],  32, lane);
    const float r4 = merge_red(acc[8],  acc[9],  32, lane);
    const float r5 = merge_red(acc[10], acc[11], 32, lane);
    const float s0 = merge_red(r0, r1, 16, lane);
    const float s1 = merge_red(r2, r3, 16, lane);
    const float s2 = merge_red(r4, r5, 16, lane);
    const float t0 = merge_red(s0, s1, 8, lane);
    const float t1 = s2 + __shfl_xor(s2, 8, 64);
    float u = merge_red(t0, t1, 4, lane);
    u += __shfl_xor(u, 2, 64);
    u += __shfl_xor(u, 1, 64);
    return u;
}

// One block per anchor PAIR (R10 structure). THIS ROUND'S DELTA: all 10 streamed
// row-loads are forced into registers BEFORE any distance math via
// sched_barrier(0) — every prior variant sat at VGPR=28-32 (compiler recycling
// 2-3 load buffers -> ~3 loads in flight -> exposed L2/HBM latency, the last
// unexplained ~7us). ~56 VGPR of load buffers => 14 loads in flight per wave.
__global__ __launch_bounds__(256) void hinge_kernel(const float* __restrict__ vfeat,
                                                    const float* __restrict__ afeat,
                                                    float* __restrict__ bsum,
                                                    int B, int nblocks) {
    // XCD-chunked bijective swizzle (R2: -46%): contiguous anchors per XCD.
    int b = blockIdx.x;
    if ((nblocks & 7) == 0) {
        const int chunk = nblocks >> 3;
        b = (b & 7) * chunk + (b >> 3);
    }
    const int k0 = 2 * b;
    const int k1 = k0 + 1;
    const int t = threadIdx.x;
    const int wave = t >> 6;
    const int lane = t & 63;

    const float4* __restrict__ v4 = reinterpret_cast<const float4*>(vfeat);
    const float4* __restrict__ a4 = reinterpret_cast<const float4*>(afeat);

    // acc0: anchor k0 ([0]=pos, [1..5]=n1, [6..10]=n2, [11]=pad); acc1: anchor k1
    float acc0[12], acc1[12];
    acc0[11] = 0.0f; acc1[11] = 0.0f;

    const float4 vk0 = v4[(size_t)k0 * D4 + t];
    const float4 ak0 = a4[(size_t)k0 * D4 + t];
    const float4 vk1 = v4[(size_t)k1 * D4 + t];
    const float4 ak1 = a4[(size_t)k1 * D4 + t];

    if (k0 >= SNUM) {
        // ---- load cluster: rows k0+2 .. k0+6, both matrices, into registers ----
        float4 ar[5], vr[5];
        #pragma unroll
        for (int r = 0; r < 5; ++r) {
            int row = k0 + 2 + r;
            if (row >= B) row -= B;
            ar[r] = a4[(size_t)row * D4 + t];
            vr[r] = v4[(size_t)row * D4 + t];
        }
        // fence: no compute may be hoisted above / loads sunk below
        __builtin_amdgcn_sched_barrier(0);

        // ---- compute cluster ----
        acc0[0] = sq4(vk0, ak0);
        acc1[0] = sq4(vk1, ak1);
        acc0[1] = sq4(vk0, ak1);        // k0's m=0 negative row is k1
        acc0[6] = sq4(ak0, vk1);
        #pragma unroll
        for (int r = 0; r < 4; ++r) {   // k0: rows k0+2..k0+5 (m=1..4)
            acc0[2 + r] = sq4(vk0, ar[r]);
            acc0[7 + r] = sq4(ak0, vr[r]);
        }
        #pragma unroll
        for (int r = 0; r < 5; ++r) {   // k1: rows k0+2..k0+6 (m=0..4)
            acc1[1 + r] = sq4(vk1, ar[r]);
            acc1[6 + r] = sq4(ak1, vr[r]);
        }
    } else {
        // generic path (k0 < SNUM: reference's m==k duplicate breaks contiguity)
        // — 3 blocks only; wave-uniform branch.
        acc0[0] = sq4(vk0, ak0);
        acc1[0] = sq4(vk1, ak1);
        #pragma unroll
        for (int m = 0; m < SNUM; ++m) {
            int t0 = k0 + m + 1; if (m == k0) t0 = k0 + 1; if (t0 >= B) t0 -= B;
            int t1 = k1 + m + 1; if (m == k1) t1 = k1 + 1; if (t1 >= B) t1 -= B;
            const float4 a0 = a4[(size_t)t0 * D4 + t];
            const float4 v0 = v4[(size_t)t0 * D4 + t];
            const float4 a1 = a4[(size_t)t1 * D4 + t];
            const float4 v1 = v4[(size_t)t1 * D4 + t];
            acc0[1 + m] = sq4(vk0, a0);
            acc0[6 + m] = sq4(ak0, v0);
            acc1[1 + m] = sq4(vk1, a1);
            acc1[6 + m] = sq4(ak1, v1);
        }
    }

    const float u0 = butterfly12(acc0, lane);
    const float u1 = butterfly12(acc1, lane);

    // lane -> acc id, one canonical representative lane per id
    const int b5 = (lane >> 5) & 1, b4 = (lane >> 4) & 1;
    const int b3 = (lane >> 3) & 1, b2 = (lane >> 2) & 1;
    const int id = b2 ? (8 + 2 * b4 + b5) : (4 * b3 + 2 * b4 + b5);
    const bool rep = ((lane & 3) == 0) && (!b2 || !b3);

    __shared__ float sh[4][24];
    if (rep) {
        sh[wave][id]      = u0;
        sh[wave][12 + id] = u1;
    }
    __syncthreads();

    if (t == 0) {
        float tot[22];
        #pragma unroll
        for (int i = 0; i < 11; ++i) {
            tot[i]      = sh[0][i] + sh[1][i] + sh[2][i] + sh[3][i];
            tot[11 + i] = sh[0][12 + i] + sh[1][12 + i] + sh[2][12 + i] + sh[3][12 + i];
        }
        const float dp0 = sqrtf(tot[0]);
        float dn1_0 = sqrtf(tot[1]), dn2_0 = sqrtf(tot[6]);
        const float dp1 = sqrtf(tot[11]);
        float dn1_1 = sqrtf(tot[12]), dn2_1 = sqrtf(tot[17]);
        #pragma unroll
        for (int m = 1; m < SNUM; ++m) {
            dn1_0 = fminf(dn1_0, sqrtf(tot[1 + m]));
            dn2_0 = fminf(dn2_0, sqrtf(tot[6 + m]));
            dn1_1 = fminf(dn1_1, sqrtf(tot[12 + m]));
            dn2_1 = fminf(dn2_1, sqrtf(tot[17 + m]));
        }
        const float h0 = fmaxf(MARGINL + 2.0f * dp0 - dn1_0 - dn2_0, 0.0f);
        const float h1 = fmaxf(MARGINL + 2.0f * dp1 - dn1_1 - dn2_1, 0.0f);
        bsum[blockIdx.x] = h0 + h1;
    }
}

// Deterministic single-block mean: sum n partials / B.
__global__ __launch_bounds__(1024) void mean_kernel(const float* __restrict__ bsum,
                                                    float* __restrict__ out,
                                                    int n, int B) {
    const int t = threadIdx.x;
    float s = 0.0f;
    for (int i = t; i < n; i += 1024) s += bsum[i];

    #pragma unroll
    for (int off = 32; off > 0; off >>= 1)
        s += __shfl_xor(s, off, 64);

    __shared__ float red[16];
    if ((t & 63) == 0) red[t >> 6] = s;
    __syncthreads();
    if (t == 0) {
        float tot = 0.0f;
        #pragma unroll
        for (int w = 0; w < 16; ++w) tot += red[w];
        out[0] = tot / (float)B;
    }
}

extern "C" void kernel_launch(void* const* d_in, const int* in_sizes, int n_in,
                              void* d_out, int out_size, void* d_ws, size_t ws_size,
                              hipStream_t stream) {
    const float* vfeat = (const float*)d_in[0];
    const float* afeat = (const float*)d_in[1];
    const int B = in_sizes[0] / DIM;
    const int nblocks = B / 2;

    float* bsum = (float*)d_ws;   // nblocks floats of scratch
    float* out  = (float*)d_out;

    hinge_kernel<<<nblocks, 256, 0, stream>>>(vfeat, afeat, bsum, B, nblocks);
    mean_kernel<<<1, 1024, 0, stream>>>(bsum, out, nblocks, B);
}